// Round 2
// baseline (1960.694 us; speedup 1.0000x reference)
//
#include <hip/hip_runtime.h>
#include <cstddef>

#define NQ 2048   // batch B
#define NS 20000  // stars N
#define DD 64     // feature dim
#define DY 32     // label dim
#define LL 100    // unique labels
#define NC1 64    // split-K chunks for k_star
#define NC2 64    // split-K chunks for k_out
#define CH1 320   // ceil(NS/NC1) rounded to 8
#define CH2 320

// sum over the 4 lanes of a quad (lanes differing in bits 0-1) via DPP quad_perm
__device__ __forceinline__ float quad_sum(float v) {
  v += __int_as_float(__builtin_amdgcn_update_dpp(
      0, __float_as_int(v), 0xB1 /*[1,0,3,2]*/, 0xF, 0xF, true));
  v += __int_as_float(__builtin_amdgcn_update_dpp(
      0, __float_as_int(v), 0x4E /*[2,3,0,1]*/, 0xF, 0xF, true));
  return v;
}

// ---------------- K0: norms, exp(-eta*ld) tables, matchIdx init ----------------
__global__ __launch_bounds__(256) void k_init(
    const float* __restrict__ star, const float* __restrict__ f1,
    const float* __restrict__ f2, const float* __restrict__ x,
    const float* __restrict__ ld1, const float* __restrict__ ld2,
    float* __restrict__ ns, float* __restrict__ nf1, float* __restrict__ nf2,
    float* __restrict__ nx, float* __restrict__ e1, float* __restrict__ e2,
    int* __restrict__ matchIdx)
{
  int t = blockIdx.x * 256 + threadIdx.x;
  if (t < NS) {
    const float4* a = (const float4*)(star + (size_t)t * DD);
    const float4* b = (const float4*)(f1 + (size_t)t * DD);
    const float4* c = (const float4*)(f2 + (size_t)t * DD);
    float sa = 0.f, sb = 0.f, sc = 0.f;
#pragma unroll
    for (int j = 0; j < 16; j++) {
      float4 va = a[j]; sa += va.x*va.x + va.y*va.y + va.z*va.z + va.w*va.w;
      float4 vb = b[j]; sb += vb.x*vb.x + vb.y*vb.y + vb.z*vb.z + vb.w*vb.w;
      float4 vc = c[j]; sc += vc.x*vc.x + vc.y*vc.y + vc.z*vc.z + vc.w*vc.w;
    }
    ns[t] = sa; nf1[t] = sb; nf2[t] = sc;
  } else if (t < NS + NQ) {
    int q = t - NS;
    const float4* a = (const float4*)(x + (size_t)q * DD);
    float s = 0.f;
#pragma unroll
    for (int j = 0; j < 16; j++) { float4 v = a[j]; s += v.x*v.x + v.y*v.y + v.z*v.z + v.w*v.w; }
    nx[q] = s;
    matchIdx[q] = NS;  // sentinel: no exact match
  } else if (t < NS + NQ + LL * LL) {
    int i = t - NS - NQ;
    e1[i] = __expf(-0.01f * ld1[i]);
    e2[i] = __expf(-0.01f * ld2[i]);
  }
}

// ---------------- K1: fused e_star pass, barrier-free ----------------
// lane layout: dg = lane&3 (dim group, strided float4s), col = lane>>2
// e = exp(2*dot - ns_i): the exp(-nx_b) factor cancels in the xt ratio.
// Partial dots reduced across the quad with 2 DPP adds. Results accumulated
// into global buffers with atomicAdd (<=63 adders per address).
__global__ __launch_bounds__(256) void k_star(
    const float* __restrict__ x, const float* __restrict__ star,
    const float* __restrict__ f1, const float* __restrict__ f2,
    const float* __restrict__ ns, const float* __restrict__ nx,
    float* __restrict__ xtacc1, float* __restrict__ xtacc2,
    float* __restrict__ sacc, int* __restrict__ matchIdx)
{
  const int r0 = blockIdx.y * CH1;
  if (r0 >= NS) return;
  const int r1 = min(r0 + CH1, NS);
  const int lane = threadIdx.x & 63;
  const int dg = lane & 3;
  const int b = blockIdx.x * 64 + (threadIdx.x >> 6) * 16 + (lane >> 2);

  float xr[16];
  {
    const float* xb = x + (size_t)b * DD + dg * 4;
#pragma unroll
    for (int k = 0; k < 4; k++) {
      float4 v = *(const float4*)(xb + k * 16);
      xr[4*k+0] = v.x; xr[4*k+1] = v.y; xr[4*k+2] = v.z; xr[4*k+3] = v.w;
    }
  }
  const float nxb = nx[b];
  float acc1[16], acc2[16];
#pragma unroll
  for (int j = 0; j < 16; j++) { acc1[j] = 0.f; acc2[j] = 0.f; }
  float esum = 0.f;
  int lmin = NS;

  for (int r = r0; r < r1; r += 8) {
    float ev[8];
#pragma unroll
    for (int rr = 0; rr < 8; rr++) {
      const float* sp = star + (size_t)(r + rr) * DD + dg * 4;
      float pd = 0.f;
#pragma unroll
      for (int k = 0; k < 4; k++) {
        float4 v = *(const float4*)(sp + k * 16);
        pd += v.x*xr[4*k+0] + v.y*xr[4*k+1] + v.z*xr[4*k+2] + v.w*xr[4*k+3];
      }
      float dot = quad_sum(pd);
      float nsr = ns[r + rr];
      if (2.f * dot >= nsr + nxb) lmin = min(lmin, r + rr);  // exact match (never in practice)
      float e = __expf(__builtin_fmaf(2.f, dot, -nsr));
      ev[rr] = e;
      esum += e;
    }
#pragma unroll
    for (int rr = 0; rr < 8; rr++) {
      const float e = ev[rr];
      const float* ap = f1 + (size_t)(r + rr) * DD + dg * 4;
      const float* bp = f2 + (size_t)(r + rr) * DD + dg * 4;
#pragma unroll
      for (int k = 0; k < 4; k++) {
        float4 va = *(const float4*)(ap + k * 16);
        acc1[4*k+0] += e*va.x; acc1[4*k+1] += e*va.y;
        acc1[4*k+2] += e*va.z; acc1[4*k+3] += e*va.w;
        float4 vb = *(const float4*)(bp + k * 16);
        acc2[4*k+0] += e*vb.x; acc2[4*k+1] += e*vb.y;
        acc2[4*k+2] += e*vb.z; acc2[4*k+3] += e*vb.w;
      }
    }
  }

  float* o1 = xtacc1 + (size_t)b * DD + dg * 4;
  float* o2 = xtacc2 + (size_t)b * DD + dg * 4;
#pragma unroll
  for (int k = 0; k < 4; k++)
#pragma unroll
    for (int j = 0; j < 4; j++) {
      atomicAdd(o1 + k * 16 + j, acc1[4*k+j]);
      atomicAdd(o2 + k * 16 + j, acc2[4*k+j]);
    }
  if (dg == 0) atomicAdd(sacc + b, esum);
  if (lmin < NS) atomicMin(matchIdx + b, lmin);
}

// ---------------- K2: xt, y = xt@W+b, y_idx = argmin dist ----------------
__global__ __launch_bounds__(256) void k_mid(
    const float* __restrict__ xtacc1, const float* __restrict__ xtacc2,
    const float* __restrict__ sacc, const int* __restrict__ matchIdx,
    const float* __restrict__ f1, const float* __restrict__ f2,
    const float* __restrict__ W1, const float* __restrict__ b1,
    const float* __restrict__ W2, const float* __restrict__ b2,
    const float* __restrict__ u1, const float* __restrict__ u2,
    float* __restrict__ xt1, float* __restrict__ xt2,
    int* __restrict__ yid1, int* __restrict__ yid2)
{
  __shared__ float xts[2][4][64];
  __shared__ float ys[4][64];
  const int lane = threadIdx.x & 63;
  const int w = __builtin_amdgcn_readfirstlane(threadIdx.x >> 6);
  const int b = blockIdx.x * 4 + w;

  const float S = sacc[b];
  const int m = matchIdx[b];
  float xa, xb;
  if (m < NS) {  // exact match: xt = feats[match_idx]
    xa = f1[(size_t)m * DD + lane];
    xb = f2[(size_t)m * DD + lane];
  } else {
    xa = xtacc1[(size_t)b * DD + lane] / S;
    xb = xtacc2[(size_t)b * DD + lane] / S;
  }
  xt1[(size_t)b * DD + lane] = xa;
  xt2[(size_t)b * DD + lane] = xb;
  xts[0][w][lane] = xa;
  xts[1][w][lane] = xb;
  __syncthreads();

  const int half = lane >> 5;
  const int j = lane & 31;
  const float* W = half ? W2 : W1;
  float y = (half ? b2 : b1)[j];
  for (int d = 0; d < DD; d++) y += xts[half][w][d] * W[d * DY + j];
  ys[w][lane] = y;
  __syncthreads();

#pragma unroll
  for (int p = 0; p < 2; p++) {
    const float* u = p ? u2 : u1;
    unsigned long long best = ~0ull;  // pack (dist_bits<<32)|idx: min => first argmin
#pragma unroll
    for (int h = 0; h < 2; h++) {
      int l = lane + h * 64;
      if (l < LL) {
        float dist = 0.f;
        for (int jj = 0; jj < DY; jj++) {
          float diff = ys[w][p * 32 + jj] - u[(size_t)l * DY + jj];
          dist += diff * diff;
        }
        unsigned long long pk = ((unsigned long long)__float_as_uint(dist) << 32) | (unsigned)l;
        best = best < pk ? best : pk;
      }
    }
#pragma unroll
    for (int off = 32; off > 0; off >>= 1) {
      unsigned long long o = __shfl_xor(best, off, 64);
      best = best < o ? best : o;
    }
    if (lane == 0) (p ? yid2 : yid1)[b] = (int)(best & 0xffffffffull);
  }
}

// ---------------- K3: fused e2 pass, barrier-free (one branch per launch) ----------------
// e = exp(2*f.xt - nf) * exp(-eta*ld); exp(-|xt|^2) cancels in the ratio.
__global__ __launch_bounds__(256) void k_out(
    const float* __restrict__ xt, const float* __restrict__ f,
    const float* __restrict__ sl, const float* __restrict__ nf,
    const int* __restrict__ lidx, const int* __restrict__ yid,
    const float* __restrict__ eld,
    float* __restrict__ qacc, float* __restrict__ qsacc)
{
  const int r0 = blockIdx.y * CH2;
  if (r0 >= NS) return;
  const int r1 = min(r0 + CH2, NS);
  const int lane = threadIdx.x & 63;
  const int dg = lane & 3;
  const int b = blockIdx.x * 64 + (threadIdx.x >> 6) * 16 + (lane >> 2);

  float xr[16];
  {
    const float* xb = xt + (size_t)b * DD + dg * 4;
#pragma unroll
    for (int k = 0; k < 4; k++) {
      float4 v = *(const float4*)(xb + k * 16);
      xr[4*k+0] = v.x; xr[4*k+1] = v.y; xr[4*k+2] = v.z; xr[4*k+3] = v.w;
    }
  }
  const int yc = yid[b];
  float acc[8];
#pragma unroll
  for (int j = 0; j < 8; j++) acc[j] = 0.f;
  float es = 0.f;

  for (int r = r0; r < r1; r += 8) {
    float ev[8];
#pragma unroll
    for (int rr = 0; rr < 8; rr++) {
      const float* fp = f + (size_t)(r + rr) * DD + dg * 4;
      float pd = 0.f;
#pragma unroll
      for (int k = 0; k < 4; k++) {
        float4 v = *(const float4*)(fp + k * 16);
        pd += v.x*xr[4*k+0] + v.y*xr[4*k+1] + v.z*xr[4*k+2] + v.w*xr[4*k+3];
      }
      float dot = quad_sum(pd);
      float e = __expf(__builtin_fmaf(2.f, dot, -nf[r + rr])) * eld[lidx[r + rr] * LL + yc];
      ev[rr] = e;
      es += e;
    }
#pragma unroll
    for (int rr = 0; rr < 8; rr++) {
      const float e = ev[rr];
      const float* sp = sl + (size_t)(r + rr) * DY + dg * 4;
#pragma unroll
      for (int k = 0; k < 2; k++) {
        float4 v = *(const float4*)(sp + k * 16);
        acc[4*k+0] += e*v.x; acc[4*k+1] += e*v.y;
        acc[4*k+2] += e*v.z; acc[4*k+3] += e*v.w;
      }
    }
  }

  float* o = qacc + (size_t)b * DY + dg * 4;
#pragma unroll
  for (int k = 0; k < 2; k++)
#pragma unroll
    for (int j = 0; j < 4; j++)
      atomicAdd(o + k * 16 + j, acc[4*k+j]);
  if (dg == 0) atomicAdd(qsacc + b, es);
}

// ---------------- K4: final divide + average of branches ----------------
__global__ __launch_bounds__(256) void k_fin(
    const float* __restrict__ q1, const float* __restrict__ qs1,
    const float* __restrict__ q2, const float* __restrict__ qs2,
    float* __restrict__ out)
{
  int t = blockIdx.x * 256 + threadIdx.x;
  if (t >= NQ * DY) return;
  int b = t >> 5;
  out[t] = 0.5f * (q1[t] / qs1[b] + q2[t] / qs2[b]);
}

extern "C" void kernel_launch(void* const* d_in, const int* in_sizes, int n_in,
                              void* d_out, int out_size, void* d_ws, size_t ws_size,
                              hipStream_t stream)
{
  const float* x    = (const float*)d_in[0];
  const float* star = (const float*)d_in[1];
  const float* slab = (const float*)d_in[2];
  const float* f1   = (const float*)d_in[3];
  const float* f2   = (const float*)d_in[4];
  const float* u1   = (const float*)d_in[5];
  const float* u2   = (const float*)d_in[6];
  const float* ld1  = (const float*)d_in[7];
  const float* ld2  = (const float*)d_in[8];
  const float* W1   = (const float*)d_in[9];
  const float* b1   = (const float*)d_in[10];
  const float* W2   = (const float*)d_in[11];
  const float* b2   = (const float*)d_in[12];
  const int* lidx1  = (const int*)d_in[13];
  const int* lidx2  = (const int*)d_in[14];
  float* out = (float*)d_out;

  // workspace layout (floats); atomic accumulators first (one memset region)
  float* p = (float*)d_ws;
  float* xtacc1 = p; p += (size_t)NQ * DD;   // 131072
  float* xtacc2 = p; p += (size_t)NQ * DD;
  float* qacc1  = p; p += (size_t)NQ * DY;   // 65536
  float* qacc2  = p; p += (size_t)NQ * DY;
  float* sacc   = p; p += NQ;
  float* qsacc1 = p; p += NQ;
  float* qsacc2 = p; p += NQ;
  const size_t zeroN = (size_t)(p - (float*)d_ws);
  float* xt1 = p; p += (size_t)NQ * DD;
  float* xt2 = p; p += (size_t)NQ * DD;
  float* ns  = p; p += NS;
  float* nf1 = p; p += NS;
  float* nf2 = p; p += NS;
  float* nx  = p; p += NQ;
  float* e1  = p; p += LL * LL;
  float* e2  = p; p += LL * LL;
  int* matchIdx = (int*)p; p += NQ;
  int* yid1 = (int*)p; p += NQ;
  int* yid2 = (int*)p;

  hipMemsetAsync(d_ws, 0, zeroN * sizeof(float), stream);
  k_init<<<(NS + NQ + LL * LL + 255) / 256, 256, 0, stream>>>(
      star, f1, f2, x, ld1, ld2, ns, nf1, nf2, nx, e1, e2, matchIdx);
  k_star<<<dim3(NQ / 64, NC1), 256, 0, stream>>>(
      x, star, f1, f2, ns, nx, xtacc1, xtacc2, sacc, matchIdx);
  k_mid<<<NQ / 4, 256, 0, stream>>>(
      xtacc1, xtacc2, sacc, matchIdx, f1, f2, W1, b1, W2, b2, u1, u2,
      xt1, xt2, yid1, yid2);
  k_out<<<dim3(NQ / 64, NC2), 256, 0, stream>>>(
      xt1, f1, slab, nf1, lidx1, yid1, e1, qacc1, qsacc1);
  k_out<<<dim3(NQ / 64, NC2), 256, 0, stream>>>(
      xt2, f2, slab, nf2, lidx2, yid2, e2, qacc2, qsacc2);
  k_fin<<<(NQ * DY + 255) / 256, 256, 0, stream>>>(qacc1, qsacc1, qacc2, qsacc2, out);
}

// Round 3
// 437.925 us; speedup vs baseline: 4.4772x; 4.4772x over previous
//
#include <hip/hip_runtime.h>
#include <cstddef>

#define NQ 2048    // batch B
#define NS 20000   // stars N
#define NSP 20032  // NS padded to 64
#define DD 64      // feature dim
#define DY 32      // label dim
#define LL 100     // unique labels
#define NT 313     // i-tiles of 64 (NSP/64)
#define NCH 16     // split-i chunks
#define TPC 20     // tiles per chunk (ceil(313/16))
#define LOG2E 1.4426950408889634f

typedef __attribute__((ext_vector_type(8))) short bfrag;   // 8 bf16 (A/B operand)
typedef __attribute__((ext_vector_type(4))) float ffrag;   // 4 f32  (C/D operand)

#if __has_builtin(__builtin_amdgcn_exp2f)
#define EXP2(x) __builtin_amdgcn_exp2f(x)
#else
#define EXP2(x) exp2f(x)
#endif

// fp32 -> bf16 (RNE), returned as raw ushort
__device__ __forceinline__ unsigned short bf16rne(float v) {
  unsigned int u = __float_as_uint(v);
  u += 0x7FFFu + ((u >> 16) & 1u);
  return (unsigned short)(u >> 16);
}

// ---------------- K0: convert/transposes/norms/tables ----------------
// R1: bf16 row-major star/f1/f2  R2: norms(*log2e, pad=1e30)
// R3: vt1 [144][NSP] = [f1^T;f2^T;ones;0], vt2 [48][NSP] = [sl^T;ones;0], lidx pad-copies
// R4: xb = bf16(x*2log2e)  R5: nxl, matchIdx  R6: eld tables
__global__ __launch_bounds__(256) void k_prep(
    const float* __restrict__ x, const float* __restrict__ star,
    const float* __restrict__ slab, const float* __restrict__ f1,
    const float* __restrict__ f2, const float* __restrict__ ld1,
    const float* __restrict__ ld2, const int* __restrict__ lidx1,
    const int* __restrict__ lidx2,
    unsigned short* __restrict__ star_b, unsigned short* __restrict__ f1_rm,
    unsigned short* __restrict__ f2_rm, unsigned short* __restrict__ vt1,
    unsigned short* __restrict__ vt2, unsigned short* __restrict__ xb,
    float* __restrict__ nsl, float* __restrict__ nf1l, float* __restrict__ nf2l,
    float* __restrict__ nxl, float* __restrict__ eld1, float* __restrict__ eld2,
    int* __restrict__ lidxp1, int* __restrict__ lidxp2, int* __restrict__ matchIdx)
{
  const int R1 = NSP * 8, R2 = NSP, R3 = NSP, R4 = NQ * 8, R5 = NQ;
  int t = blockIdx.x * 256 + threadIdx.x;
  if (t < R1) {
    int i = t >> 3, dg = t & 7;
    unsigned short o[3][8];
    if (i < NS) {
      const float* ps = star + (size_t)i * DD + dg * 8;
      const float* pa = f1 + (size_t)i * DD + dg * 8;
      const float* pb = f2 + (size_t)i * DD + dg * 8;
#pragma unroll
      for (int j = 0; j < 8; j++) {
        o[0][j] = bf16rne(ps[j]); o[1][j] = bf16rne(pa[j]); o[2][j] = bf16rne(pb[j]);
      }
    } else {
#pragma unroll
      for (int j = 0; j < 8; j++) { o[0][j] = 0; o[1][j] = 0; o[2][j] = 0; }
    }
    size_t off = (size_t)i * DD + dg * 8;
#pragma unroll
    for (int j = 0; j < 8; j++) {
      star_b[off + j] = o[0][j]; f1_rm[off + j] = o[1][j]; f2_rm[off + j] = o[2][j];
    }
    return;
  }
  t -= R1;
  if (t < R2) {
    int i = t;
    if (i < NS) {
      float sa = 0.f, sb = 0.f, sc = 0.f;
      const float* ps = star + (size_t)i * DD;
      const float* pa = f1 + (size_t)i * DD;
      const float* pb = f2 + (size_t)i * DD;
      for (int d = 0; d < DD; d++) {
        sa += ps[d]*ps[d]; sb += pa[d]*pa[d]; sc += pb[d]*pb[d];
      }
      nsl[i] = LOG2E * sa; nf1l[i] = LOG2E * sb; nf2l[i] = LOG2E * sc;
    } else {
      nsl[i] = 1e30f; nf1l[i] = 1e30f; nf2l[i] = 1e30f;
    }
    return;
  }
  t -= R2;
  if (t < R3) {
    int i = t;
    bool ok = i < NS;
    // vt1: rows 0-63 f1^T, 64-127 f2^T, 128 ones, 129-143 zero
    for (int d = 0; d < DD; d++)
      vt1[(size_t)d * NSP + i] = ok ? bf16rne(f1[(size_t)i * DD + d]) : 0;
    for (int d = 0; d < DD; d++)
      vt1[(size_t)(DD + d) * NSP + i] = ok ? bf16rne(f2[(size_t)i * DD + d]) : 0;
    vt1[(size_t)128 * NSP + i] = ok ? 0x3F80 : 0;
    for (int d = 129; d < 144; d++) vt1[(size_t)d * NSP + i] = 0;
    // vt2: rows 0-31 sl^T, 32 ones, 33-47 zero
    for (int d = 0; d < DY; d++)
      vt2[(size_t)d * NSP + i] = ok ? bf16rne(slab[(size_t)i * DY + d]) : 0;
    vt2[(size_t)DY * NSP + i] = ok ? 0x3F80 : 0;
    for (int d = DY + 1; d < 48; d++) vt2[(size_t)d * NSP + i] = 0;
    lidxp1[i] = ok ? lidx1[i] : 0;
    lidxp2[i] = ok ? lidx2[i] : 0;
    return;
  }
  t -= R3;
  if (t < R4) {
    int b = t >> 3, dg = t & 7;
    const float* px = x + (size_t)b * DD + dg * 8;
#pragma unroll
    for (int j = 0; j < 8; j++)
      xb[(size_t)b * DD + dg * 8 + j] = bf16rne(px[j] * (2.f * LOG2E));
    return;
  }
  t -= R4;
  if (t < R5) {
    int b = t;
    float s = 0.f;
    const float* px = x + (size_t)b * DD;
    for (int d = 0; d < DD; d++) s += px[d] * px[d];
    nxl[b] = LOG2E * s;
    matchIdx[b] = NS;
    return;
  }
  t -= R5;
  if (t < LL * LL) {
    eld1[t] = __expf(-0.01f * ld1[t]);
    eld2[t] = __expf(-0.01f * ld2[t]);
  }
}

// ---------------- K1: flash-style e_star pass ----------------
// GEMM1 (swapped): S^T[i,b] = star_b . xb  (xb pre-scaled by 2*log2e)
// P = exp2(S - nsl[i]); GEMM2: XT[b, 0..143] += P . vt1  (col 128 = e-sum)
__global__ __launch_bounds__(256, 2) void k_star(
    const unsigned short* __restrict__ xb, const unsigned short* __restrict__ star_b,
    const unsigned short* __restrict__ vt1, const float* __restrict__ nsl,
    const float* __restrict__ nxl,
    float* __restrict__ xtacc1, float* __restrict__ xtacc2,
    float* __restrict__ sacc, int* __restrict__ matchIdx)
{
  __shared__ __align__(16) unsigned short plds[4][16 * 88];  // per-wave P tile, stride 176B
  const int w = threadIdx.x >> 6, lane = threadIdx.x & 63;
  const int col = lane & 15, quad = lane >> 4;
  const int b0 = blockIdx.x * 64 + w * 16;
  const int bq = b0 + col;
  unsigned short* myp = &plds[w][0];

  bfrag xf0 = *(const bfrag*)(xb + (size_t)bq * DD + quad * 8);
  bfrag xf1 = *(const bfrag*)(xb + (size_t)bq * DD + 32 + quad * 8);
  const float nxlb = nxl[bq];

  ffrag acc[9];
#pragma unroll
  for (int n = 0; n < 9; n++) acc[n] = (ffrag){0.f, 0.f, 0.f, 0.f};
  int lmin = NS;

  const int t0 = blockIdx.y * TPC;
  const int t1 = min(t0 + TPC, NT);
  for (int t = t0; t < t1; ++t) {
    const int i0 = t * 64;
#pragma unroll
    for (int m = 0; m < 4; m++) {
      const int ib = i0 + m * 16;
      bfrag a0 = *(const bfrag*)(star_b + (size_t)(ib + col) * DD + quad * 8);
      bfrag a1 = *(const bfrag*)(star_b + (size_t)(ib + col) * DD + 32 + quad * 8);
      ffrag c = (ffrag){0.f, 0.f, 0.f, 0.f};
      c = __builtin_amdgcn_mfma_f32_16x16x32_bf16(a0, xf0, c, 0, 0, 0);
      c = __builtin_amdgcn_mfma_f32_16x16x32_bf16(a1, xf1, c, 0, 0, 0);
      float4 nsv = *(const float4*)(nsl + ib + quad * 4);
      float e0 = c[0] - nsv.x, e1 = c[1] - nsv.y, e2 = c[2] - nsv.z, e3 = c[3] - nsv.w;
      int ibase = ib + quad * 4;
      if (e0 >= nxlb) lmin = min(lmin, ibase + 0);
      if (e1 >= nxlb) lmin = min(lmin, ibase + 1);
      if (e2 >= nxlb) lmin = min(lmin, ibase + 2);
      if (e3 >= nxlb) lmin = min(lmin, ibase + 3);
      e0 = EXP2(e0); e1 = EXP2(e1); e2 = EXP2(e2); e3 = EXP2(e3);
      unsigned int p01 = (unsigned int)bf16rne(e0) | ((unsigned int)bf16rne(e1) << 16);
      unsigned int p23 = (unsigned int)bf16rne(e2) | ((unsigned int)bf16rne(e3) << 16);
      *(uint2*)(myp + col * 88 + m * 16 + quad * 4) = make_uint2(p01, p23);
    }
    // wave-private LDS: compiler's lgkmcnt ordering suffices (no barrier)
    bfrag pa0 = *(const bfrag*)(myp + col * 88 + quad * 8);
    bfrag pa1 = *(const bfrag*)(myp + col * 88 + 32 + quad * 8);
#pragma unroll
    for (int n = 0; n < 9; n++) {
      bfrag v0 = *(const bfrag*)(vt1 + (size_t)(n * 16 + col) * NSP + i0 + quad * 8);
      bfrag v1 = *(const bfrag*)(vt1 + (size_t)(n * 16 + col) * NSP + i0 + 32 + quad * 8);
      acc[n] = __builtin_amdgcn_mfma_f32_16x16x32_bf16(pa0, v0, acc[n], 0, 0, 0);
      acc[n] = __builtin_amdgcn_mfma_f32_16x16x32_bf16(pa1, v1, acc[n], 0, 0, 0);
    }
  }

  const int brow = b0 + quad * 4;
#pragma unroll
  for (int n = 0; n < 8; n++) {
    float* dst = (n < 4) ? (xtacc1 + n * 16 + col) : (xtacc2 + (n - 4) * 16 + col);
#pragma unroll
    for (int r = 0; r < 4; r++)
      atomicAdd(dst + (size_t)(brow + r) * DD, acc[n][r]);
  }
  if (col == 0) {
#pragma unroll
    for (int r = 0; r < 4; r++) atomicAdd(sacc + brow + r, acc[8][r]);
  }
  if (lmin < NS) atomicMin(matchIdx + bq, lmin);
}

// ---------------- K2: xt, xtb(bf16 scaled), y = xt@W+b, y_idx ----------------
__global__ __launch_bounds__(256) void k_mid(
    const float* __restrict__ xtacc1, const float* __restrict__ xtacc2,
    const float* __restrict__ sacc, const int* __restrict__ matchIdx,
    const float* __restrict__ f1, const float* __restrict__ f2,
    const float* __restrict__ W1, const float* __restrict__ b1,
    const float* __restrict__ W2, const float* __restrict__ b2,
    const float* __restrict__ u1, const float* __restrict__ u2,
    unsigned short* __restrict__ xtb1, unsigned short* __restrict__ xtb2,
    int* __restrict__ yid1, int* __restrict__ yid2)
{
  __shared__ float xts[2][4][64];
  __shared__ float ys[4][64];
  const int lane = threadIdx.x & 63;
  const int w = __builtin_amdgcn_readfirstlane(threadIdx.x >> 6);
  const int b = blockIdx.x * 4 + w;

  const float S = sacc[b];
  const int m = matchIdx[b];
  float xa, xb_;
  if (m < NS) {
    xa = f1[(size_t)m * DD + lane];
    xb_ = f2[(size_t)m * DD + lane];
  } else {
    xa = xtacc1[(size_t)b * DD + lane] / S;
    xb_ = xtacc2[(size_t)b * DD + lane] / S;
  }
  xtb1[(size_t)b * DD + lane] = bf16rne(xa * (2.f * LOG2E));
  xtb2[(size_t)b * DD + lane] = bf16rne(xb_ * (2.f * LOG2E));
  xts[0][w][lane] = xa;
  xts[1][w][lane] = xb_;
  __syncthreads();

  const int half = lane >> 5;
  const int j = lane & 31;
  const float* W = half ? W2 : W1;
  float y = (half ? b2 : b1)[j];
  for (int d = 0; d < DD; d++) y += xts[half][w][d] * W[d * DY + j];
  ys[w][lane] = y;
  __syncthreads();

#pragma unroll
  for (int p = 0; p < 2; p++) {
    const float* u = p ? u2 : u1;
    unsigned long long best = ~0ull;
#pragma unroll
    for (int h = 0; h < 2; h++) {
      int l = lane + h * 64;
      if (l < LL) {
        float dist = 0.f;
        for (int jj = 0; jj < DY; jj++) {
          float diff = ys[w][p * 32 + jj] - u[(size_t)l * DY + jj];
          dist += diff * diff;
        }
        unsigned long long pk = ((unsigned long long)__float_as_uint(dist) << 32) | (unsigned)l;
        best = best < pk ? best : pk;
      }
    }
#pragma unroll
    for (int off = 32; off > 0; off >>= 1) {
      unsigned long long o = __shfl_xor(best, off, 64);
      best = best < o ? best : o;
    }
    if (lane == 0) (p ? yid2 : yid1)[b] = (int)(best & 0xffffffffull);
  }
}

// ---------------- K3: flash-style e2 pass (one branch per launch) ----------------
__global__ __launch_bounds__(256, 2) void k_out(
    const unsigned short* __restrict__ xtb, const unsigned short* __restrict__ f_rm,
    const unsigned short* __restrict__ vt2, const float* __restrict__ nfl,
    const int* __restrict__ lidxp, const int* __restrict__ yid,
    const float* __restrict__ eld_g,
    float* __restrict__ qacc, float* __restrict__ qsacc)
{
  __shared__ float eld[LL * LL];
  __shared__ __align__(16) unsigned short plds[4][16 * 88];
  const int tid = threadIdx.x;
  for (int i = tid * 4; i < LL * LL; i += 1024)
    *(float4*)(eld + i) = *(const float4*)(eld_g + i);
  __syncthreads();

  const int w = tid >> 6, lane = tid & 63;
  const int col = lane & 15, quad = lane >> 4;
  const int b0 = blockIdx.x * 64 + w * 16;
  const int bq = b0 + col;
  unsigned short* myp = &plds[w][0];

  bfrag xf0 = *(const bfrag*)(xtb + (size_t)bq * DD + quad * 8);
  bfrag xf1 = *(const bfrag*)(xtb + (size_t)bq * DD + 32 + quad * 8);
  const int yc = yid[bq];

  ffrag acc[3];
#pragma unroll
  for (int n = 0; n < 3; n++) acc[n] = (ffrag){0.f, 0.f, 0.f, 0.f};

  const int t0 = blockIdx.y * TPC;
  const int t1 = min(t0 + TPC, NT);
  for (int t = t0; t < t1; ++t) {
    const int i0 = t * 64;
#pragma unroll
    for (int m = 0; m < 4; m++) {
      const int ib = i0 + m * 16;
      bfrag a0 = *(const bfrag*)(f_rm + (size_t)(ib + col) * DD + quad * 8);
      bfrag a1 = *(const bfrag*)(f_rm + (size_t)(ib + col) * DD + 32 + quad * 8);
      ffrag c = (ffrag){0.f, 0.f, 0.f, 0.f};
      c = __builtin_amdgcn_mfma_f32_16x16x32_bf16(a0, xf0, c, 0, 0, 0);
      c = __builtin_amdgcn_mfma_f32_16x16x32_bf16(a1, xf1, c, 0, 0, 0);
      float4 nfv = *(const float4*)(nfl + ib + quad * 4);
      int4 lv = *(const int4*)(lidxp + ib + quad * 4);
      float e0 = EXP2(c[0] - nfv.x) * eld[lv.x * LL + yc];
      float e1 = EXP2(c[1] - nfv.y) * eld[lv.y * LL + yc];
      float e2 = EXP2(c[2] - nfv.z) * eld[lv.z * LL + yc];
      float e3 = EXP2(c[3] - nfv.w) * eld[lv.w * LL + yc];
      unsigned int p01 = (unsigned int)bf16rne(e0) | ((unsigned int)bf16rne(e1) << 16);
      unsigned int p23 = (unsigned int)bf16rne(e2) | ((unsigned int)bf16rne(e3) << 16);
      *(uint2*)(myp + col * 88 + m * 16 + quad * 4) = make_uint2(p01, p23);
    }
    bfrag pa0 = *(const bfrag*)(myp + col * 88 + quad * 8);
    bfrag pa1 = *(const bfrag*)(myp + col * 88 + 32 + quad * 8);
#pragma unroll
    for (int n = 0; n < 3; n++) {
      bfrag v0 = *(const bfrag*)(vt2 + (size_t)(n * 16 + col) * NSP + i0 + quad * 8);
      bfrag v1 = *(const bfrag*)(vt2 + (size_t)(n * 16 + col) * NSP + i0 + 32 + quad * 8);
      acc[n] = __builtin_amdgcn_mfma_f32_16x16x32_bf16(pa0, v0, acc[n], 0, 0, 0);
      acc[n] = __builtin_amdgcn_mfma_f32_16x16x32_bf16(pa1, v1, acc[n], 0, 0, 0);
    }
  }

  const int brow = b0 + quad * 4;
#pragma unroll
  for (int n = 0; n < 2; n++)
#pragma unroll
    for (int r = 0; r < 4; r++)
      atomicAdd(qacc + (size_t)(brow + r) * DY + n * 16 + col, acc[n][r]);
  if (col == 0) {
#pragma unroll
    for (int r = 0; r < 4; r++) atomicAdd(qsacc + brow + r, acc[2][r]);
  }
}

// ---------------- K4: final divide + average ----------------
__global__ __launch_bounds__(256) void k_fin(
    const float* __restrict__ q1, const float* __restrict__ qs1,
    const float* __restrict__ q2, const float* __restrict__ qs2,
    float* __restrict__ out)
{
  int t = blockIdx.x * 256 + threadIdx.x;
  if (t >= NQ * DY) return;
  int b = t >> 5;
  out[t] = 0.5f * (q1[t] / qs1[b] + q2[t] / qs2[b]);
}

extern "C" void kernel_launch(void* const* d_in, const int* in_sizes, int n_in,
                              void* d_out, int out_size, void* d_ws, size_t ws_size,
                              hipStream_t stream)
{
  const float* x    = (const float*)d_in[0];
  const float* star = (const float*)d_in[1];
  const float* slab = (const float*)d_in[2];
  const float* f1   = (const float*)d_in[3];
  const float* f2   = (const float*)d_in[4];
  const float* u1   = (const float*)d_in[5];
  const float* u2   = (const float*)d_in[6];
  const float* ld1  = (const float*)d_in[7];
  const float* ld2  = (const float*)d_in[8];
  const float* W1   = (const float*)d_in[9];
  const float* b1   = (const float*)d_in[10];
  const float* W2   = (const float*)d_in[11];
  const float* b2   = (const float*)d_in[12];
  const int* lidx1  = (const int*)d_in[13];
  const int* lidx2  = (const int*)d_in[14];
  float* out = (float*)d_out;

  char* base = (char*)d_ws;
  size_t off = 0;
  auto alloc = [&](size_t bytes) -> char* {
    char* p = base + off;
    off = (off + bytes + 255) & ~(size_t)255;
    return p;
  };
  // zeroed accumulators first (single memset region)
  float* xtacc1 = (float*)alloc(NQ * DD * 4);
  float* xtacc2 = (float*)alloc(NQ * DD * 4);
  float* qacc1  = (float*)alloc(NQ * DY * 4);
  float* qacc2  = (float*)alloc(NQ * DY * 4);
  float* sacc   = (float*)alloc(NQ * 4);
  float* qsacc1 = (float*)alloc(NQ * 4);
  float* qsacc2 = (float*)alloc(NQ * 4);
  const size_t zeroBytes = off;
  unsigned short* xb     = (unsigned short*)alloc((size_t)NQ * DD * 2);
  unsigned short* star_b = (unsigned short*)alloc((size_t)NSP * DD * 2);
  unsigned short* f1_rm  = (unsigned short*)alloc((size_t)NSP * DD * 2);
  unsigned short* f2_rm  = (unsigned short*)alloc((size_t)NSP * DD * 2);
  unsigned short* vt1    = (unsigned short*)alloc((size_t)144 * NSP * 2);
  unsigned short* vt2    = (unsigned short*)alloc((size_t)48 * NSP * 2);
  unsigned short* xtb1   = (unsigned short*)alloc((size_t)NQ * DD * 2);
  unsigned short* xtb2   = (unsigned short*)alloc((size_t)NQ * DD * 2);
  float* nsl  = (float*)alloc(NSP * 4);
  float* nf1l = (float*)alloc(NSP * 4);
  float* nf2l = (float*)alloc(NSP * 4);
  float* nxl  = (float*)alloc(NQ * 4);
  float* eld1 = (float*)alloc(LL * LL * 4);
  float* eld2 = (float*)alloc(LL * LL * 4);
  int* lidxp1 = (int*)alloc(NSP * 4);
  int* lidxp2 = (int*)alloc(NSP * 4);
  int* matchIdx = (int*)alloc(NQ * 4);
  int* yid1 = (int*)alloc(NQ * 4);
  int* yid2 = (int*)alloc(NQ * 4);

  hipMemsetAsync(d_ws, 0, zeroBytes, stream);

  const int prepT = NSP * 8 + NSP + NSP + NQ * 8 + NQ + LL * LL;
  k_prep<<<(prepT + 255) / 256, 256, 0, stream>>>(
      x, star, slab, f1, f2, ld1, ld2, lidx1, lidx2,
      star_b, f1_rm, f2_rm, vt1, vt2, xb,
      nsl, nf1l, nf2l, nxl, eld1, eld2, lidxp1, lidxp2, matchIdx);

  k_star<<<dim3(NQ / 64, NCH), 256, 0, stream>>>(
      xb, star_b, vt1, nsl, nxl, xtacc1, xtacc2, sacc, matchIdx);

  k_mid<<<NQ / 4, 256, 0, stream>>>(
      xtacc1, xtacc2, sacc, matchIdx, f1, f2, W1, b1, W2, b2, u1, u2,
      xtb1, xtb2, yid1, yid2);

  k_out<<<dim3(NQ / 64, NCH), 256, 0, stream>>>(
      xtb1, f1_rm, vt2, nf1l, lidxp1, yid1, eld1, qacc1, qsacc1);
  k_out<<<dim3(NQ / 64, NCH), 256, 0, stream>>>(
      xtb2, f2_rm, vt2, nf2l, lidxp2, yid2, eld2, qacc2, qsacc2);

  k_fin<<<(NQ * DY + 255) / 256, 256, 0, stream>>>(qacc1, qsacc1, qacc2, qsacc2, out);
}

// Round 4
// 437.586 us; speedup vs baseline: 4.4807x; 1.0008x over previous
//
#include <hip/hip_runtime.h>
#include <cstddef>

#define NQ 2048    // batch B
#define NS 20000   // stars N
#define NSP 20032  // NS padded to 64
#define DD 64      // feature dim
#define DY 32      // label dim
#define LL 100     // unique labels
#define NT 313     // i-tiles of 64 (NSP/64)
#define NCH 48     // split-i chunks
#define TPC 7      // tiles per chunk (ceil(313/48))
#define PSTR 72    // P-tile LDS row stride in shorts (even bank spread for b128)
#define LOG2E 1.4426950408889634f

typedef __attribute__((ext_vector_type(8))) short bfrag;   // 8 bf16 (A/B operand)
typedef __attribute__((ext_vector_type(4))) float ffrag;   // 4 f32  (C/D operand)

#if __has_builtin(__builtin_amdgcn_exp2f)
#define EXP2(x) __builtin_amdgcn_exp2f(x)
#else
#define EXP2(x) exp2f(x)
#endif

// fp32 -> bf16 (RNE), raw ushort
__device__ __forceinline__ unsigned short bf16rne(float v) {
  unsigned int u = __float_as_uint(v);
  u += 0x7FFFu + ((u >> 16) & 1u);
  return (unsigned short)(u >> 16);
}

__device__ __forceinline__ uint4 pack8(const unsigned short* o) {
  uint4 q;
  q.x = (unsigned int)o[0] | ((unsigned int)o[1] << 16);
  q.y = (unsigned int)o[2] | ((unsigned int)o[3] << 16);
  q.z = (unsigned int)o[4] | ((unsigned int)o[5] << 16);
  q.w = (unsigned int)o[6] | ((unsigned int)o[7] << 16);
  return q;
}

// ---------------- prepA: per 64-i tile: bf16 row-major converts, norms, LDS transposes ----------------
__global__ __launch_bounds__(256) void k_prepA(
    const float* __restrict__ star, const float* __restrict__ f1,
    const float* __restrict__ f2, const float* __restrict__ slab,
    const int* __restrict__ lidx1, const int* __restrict__ lidx2,
    unsigned short* __restrict__ star_b, unsigned short* __restrict__ f1_rm,
    unsigned short* __restrict__ f2_rm, unsigned short* __restrict__ vt1,
    unsigned short* __restrict__ vt2,
    float* __restrict__ nsl, float* __restrict__ nf1l, float* __restrict__ nf2l,
    int* __restrict__ lidxp1, int* __restrict__ lidxp2)
{
  __shared__ float tile[64][65];
  const int i0 = blockIdx.x * 64;
  const int tid = threadIdx.x;
  const int r = tid >> 2, cs = (tid & 3) * 16;   // load role
  const int dT = tid >> 2, is = (tid & 3) * 16;  // transpose role
  const bool okr = (i0 + r) < NS;

  const float* srcs[3] = {star, f1, f2};
  unsigned short* dsts[3] = {star_b, f1_rm, f2_rm};
  float* norms[3] = {nsl, nf1l, nf2l};
#pragma unroll 1
  for (int a = 0; a < 3; a++) {
    float v[16];
    const float* src = srcs[a] + (size_t)(i0 + r) * DD + cs;
#pragma unroll
    for (int q = 0; q < 4; q++) {
      float4 t4 = okr ? *(const float4*)(src + q * 4) : make_float4(0.f, 0.f, 0.f, 0.f);
      v[4*q+0] = t4.x; v[4*q+1] = t4.y; v[4*q+2] = t4.z; v[4*q+3] = t4.w;
    }
    unsigned short ob[16];
#pragma unroll
    for (int j = 0; j < 16; j++) { ob[j] = bf16rne(v[j]); tile[r][cs + j] = v[j]; }
    *(uint4*)(dsts[a] + (size_t)(i0 + r) * DD + cs) = pack8(ob);
    *(uint4*)(dsts[a] + (size_t)(i0 + r) * DD + cs + 8) = pack8(ob + 8);
    __syncthreads();
    if (tid < 64) {
      float s = 0.f;
      for (int d = 0; d < DD; d++) s += tile[tid][d] * tile[tid][d];
      norms[a][i0 + tid] = (i0 + tid) < NS ? LOG2E * s : 1e30f;
    }
    if (a > 0) {  // transpose into vt1 rows (a==1: 0..63, a==2: 64..127)
      unsigned short tb[16];
#pragma unroll
      for (int j = 0; j < 16; j++) tb[j] = bf16rne(tile[is + j][dT]);
      unsigned short* dst = vt1 + (size_t)((a - 1) * DD + dT) * NSP + i0 + is;
      *(uint4*)dst = pack8(tb);
      *(uint4*)(dst + 8) = pack8(tb + 8);
    }
    __syncthreads();
  }

  // slab (64 x 32) -> vt2 rows 0..31
  if (tid < 128) {
    const int r2 = tid >> 1, cs2 = (tid & 1) * 16;
    const bool ok2 = (i0 + r2) < NS;
    const float* src = slab + (size_t)(i0 + r2) * DY + cs2;
#pragma unroll
    for (int q = 0; q < 4; q++) {
      float4 t4 = ok2 ? *(const float4*)(src + q * 4) : make_float4(0.f, 0.f, 0.f, 0.f);
      tile[r2][cs2+4*q+0] = t4.x; tile[r2][cs2+4*q+1] = t4.y;
      tile[r2][cs2+4*q+2] = t4.z; tile[r2][cs2+4*q+3] = t4.w;
    }
  }
  __syncthreads();
  if (tid < 128) {
    const int d2 = tid >> 2, is2 = (tid & 3) * 16;  // d2 < 32
    unsigned short tb[16];
#pragma unroll
    for (int j = 0; j < 16; j++) tb[j] = bf16rne(tile[is2 + j][d2]);
    unsigned short* dst = vt2 + (size_t)d2 * NSP + i0 + is2;
    *(uint4*)dst = pack8(tb);
    *(uint4*)(dst + 8) = pack8(tb + 8);
  }
  // ones/zero pad rows: vt1 rows 128..143, vt2 rows 32..47 (16 rows x 64 cols each)
  {
    const int row = tid >> 4;             // 0..15
    const int ic = i0 + (tid & 15) * 4;   // 4 cols
    const unsigned short one_ = 0x3F80;
    unsigned short v1r = (row == 0) ? one_ : (unsigned short)0;
    unsigned int lo = (unsigned int)((ic+0) < NS ? v1r : 0) | ((unsigned int)((ic+1) < NS ? v1r : 0) << 16);
    unsigned int hi = (unsigned int)((ic+2) < NS ? v1r : 0) | ((unsigned int)((ic+3) < NS ? v1r : 0) << 16);
    *(uint2*)(vt1 + (size_t)(128 + row) * NSP + ic) = make_uint2(lo, hi);
    *(uint2*)(vt2 + (size_t)(32 + row) * NSP + ic) = make_uint2(lo, hi);
  }
  if (tid < 64) {
    int i = i0 + tid;
    bool ok = i < NS;
    lidxp1[i] = ok ? lidx1[i] : 0;
    lidxp2[i] = ok ? lidx2[i] : 0;
  }
}

// ---------------- prepB: xb = bf16(x * 2log2e), nxl, matchIdx ----------------
__global__ __launch_bounds__(256) void k_prepB(
    const float* __restrict__ x, unsigned short* __restrict__ xb,
    float* __restrict__ nxl, int* __restrict__ matchIdx)
{
  int b = blockIdx.x * 256 + threadIdx.x;
  if (b >= NQ) return;
  const float* px = x + (size_t)b * DD;
  float s = 0.f;
  for (int d = 0; d < DD; d += 4) {
    float4 v = *(const float4*)(px + d);
    s += v.x*v.x + v.y*v.y + v.z*v.z + v.w*v.w;
    unsigned int lo = (unsigned int)bf16rne(v.x * (2.f * LOG2E)) |
                      ((unsigned int)bf16rne(v.y * (2.f * LOG2E)) << 16);
    unsigned int hi = (unsigned int)bf16rne(v.z * (2.f * LOG2E)) |
                      ((unsigned int)bf16rne(v.w * (2.f * LOG2E)) << 16);
    *(uint2*)(xb + (size_t)b * DD + d) = make_uint2(lo, hi);
  }
  nxl[b] = LOG2E * s;
  matchIdx[b] = NS;
}

// ---------------- K1: flash-style e_star pass ----------------
__global__ __launch_bounds__(256, 6) void k_star(
    const unsigned short* __restrict__ xb, const unsigned short* __restrict__ star_b,
    const unsigned short* __restrict__ vt1, const float* __restrict__ nsl,
    const float* __restrict__ nxl,
    float* __restrict__ xtacc1, float* __restrict__ xtacc2,
    float* __restrict__ sacc, int* __restrict__ matchIdx)
{
  __shared__ __align__(16) unsigned short plds[4][2][16 * PSTR];  // dbuf P tile/wave
  const int t0 = blockIdx.y * TPC;
  if (t0 >= NT) return;
  const int t1 = min(t0 + TPC, NT);
  const int w = threadIdx.x >> 6, lane = threadIdx.x & 63;
  const int col = lane & 15, quad = lane >> 4;
  const int b0 = blockIdx.x * 64 + w * 16;
  const int bq = b0 + col;

  bfrag xf0 = *(const bfrag*)(xb + (size_t)bq * DD + quad * 8);
  bfrag xf1 = *(const bfrag*)(xb + (size_t)bq * DD + 32 + quad * 8);
  const float nxlb = nxl[bq];

  ffrag acc[9];
#pragma unroll
  for (int n = 0; n < 9; n++) acc[n] = (ffrag){0.f, 0.f, 0.f, 0.f};
  int lmin = NS;

  for (int t = t0; t < t1; ++t) {
    unsigned short* myp = &plds[w][t & 1][0];
    const int i0 = t * 64;
#pragma unroll
    for (int m = 0; m < 4; m++) {
      const int ib = i0 + m * 16;
      bfrag a0 = *(const bfrag*)(star_b + (size_t)(ib + col) * DD + quad * 8);
      bfrag a1 = *(const bfrag*)(star_b + (size_t)(ib + col) * DD + 32 + quad * 8);
      ffrag c = (ffrag){0.f, 0.f, 0.f, 0.f};
      c = __builtin_amdgcn_mfma_f32_16x16x32_bf16(a0, xf0, c, 0, 0, 0);
      c = __builtin_amdgcn_mfma_f32_16x16x32_bf16(a1, xf1, c, 0, 0, 0);
      float4 nsv = *(const float4*)(nsl + ib + quad * 4);
      float e0 = c[0] - nsv.x, e1 = c[1] - nsv.y, e2 = c[2] - nsv.z, e3 = c[3] - nsv.w;
      int ibase = ib + quad * 4;
      if (e0 >= nxlb) lmin = min(lmin, ibase + 0);
      if (e1 >= nxlb) lmin = min(lmin, ibase + 1);
      if (e2 >= nxlb) lmin = min(lmin, ibase + 2);
      if (e3 >= nxlb) lmin = min(lmin, ibase + 3);
      e0 = EXP2(e0); e1 = EXP2(e1); e2 = EXP2(e2); e3 = EXP2(e3);
      unsigned int p01 = (unsigned int)bf16rne(e0) | ((unsigned int)bf16rne(e1) << 16);
      unsigned int p23 = (unsigned int)bf16rne(e2) | ((unsigned int)bf16rne(e3) << 16);
      *(uint2*)(myp + col * PSTR + m * 16 + quad * 4) = make_uint2(p01, p23);
    }
    // wave-private LDS (no barrier; compiler orders via lgkmcnt)
    bfrag pa0 = *(const bfrag*)(myp + col * PSTR + quad * 8);
    bfrag pa1 = *(const bfrag*)(myp + col * PSTR + 32 + quad * 8);
#pragma unroll
    for (int n = 0; n < 9; n++) {
      bfrag v0 = *(const bfrag*)(vt1 + (size_t)(n * 16 + col) * NSP + i0 + quad * 8);
      bfrag v1 = *(const bfrag*)(vt1 + (size_t)(n * 16 + col) * NSP + i0 + 32 + quad * 8);
      acc[n] = __builtin_amdgcn_mfma_f32_16x16x32_bf16(pa0, v0, acc[n], 0, 0, 0);
      acc[n] = __builtin_amdgcn_mfma_f32_16x16x32_bf16(pa1, v1, acc[n], 0, 0, 0);
    }
  }

  const int brow = b0 + quad * 4;
#pragma unroll
  for (int n = 0; n < 8; n++) {
    float* dst = (n < 4) ? (xtacc1 + n * 16 + col) : (xtacc2 + (n - 4) * 16 + col);
#pragma unroll
    for (int r = 0; r < 4; r++)
      atomicAdd(dst + (size_t)(brow + r) * DD, acc[n][r]);
  }
  if (col == 0) {
#pragma unroll
    for (int r = 0; r < 4; r++) atomicAdd(sacc + brow + r, acc[8][r]);
  }
  if (lmin < NS) atomicMin(matchIdx + bq, lmin);
}

// ---------------- K2: xt, xtb(bf16 scaled), y = xt@W+b, y_idx ----------------
__global__ __launch_bounds__(256) void k_mid(
    const float* __restrict__ xtacc1, const float* __restrict__ xtacc2,
    const float* __restrict__ sacc, const int* __restrict__ matchIdx,
    const float* __restrict__ f1, const float* __restrict__ f2,
    const float* __restrict__ W1, const float* __restrict__ b1,
    const float* __restrict__ W2, const float* __restrict__ b2,
    const float* __restrict__ u1, const float* __restrict__ u2,
    unsigned short* __restrict__ xtb1, unsigned short* __restrict__ xtb2,
    int* __restrict__ yid1, int* __restrict__ yid2)
{
  __shared__ float xts[2][4][64];
  __shared__ float ys[4][64];
  const int lane = threadIdx.x & 63;
  const int w = __builtin_amdgcn_readfirstlane(threadIdx.x >> 6);
  const int b = blockIdx.x * 4 + w;

  const float S = sacc[b];
  const int m = matchIdx[b];
  float xa, xb_;
  if (m < NS) {
    xa = f1[(size_t)m * DD + lane];
    xb_ = f2[(size_t)m * DD + lane];
  } else {
    xa = xtacc1[(size_t)b * DD + lane] / S;
    xb_ = xtacc2[(size_t)b * DD + lane] / S;
  }
  xtb1[(size_t)b * DD + lane] = bf16rne(xa * (2.f * LOG2E));
  xtb2[(size_t)b * DD + lane] = bf16rne(xb_ * (2.f * LOG2E));
  xts[0][w][lane] = xa;
  xts[1][w][lane] = xb_;
  __syncthreads();

  const int half = lane >> 5;
  const int j = lane & 31;
  const float* W = half ? W2 : W1;
  float y = (half ? b2 : b1)[j];
  for (int d = 0; d < DD; d++) y += xts[half][w][d] * W[d * DY + j];
  ys[w][lane] = y;
  __syncthreads();

#pragma unroll
  for (int p = 0; p < 2; p++) {
    const float* u = p ? u2 : u1;
    unsigned long long best = ~0ull;
#pragma unroll
    for (int h = 0; h < 2; h++) {
      int l = lane + h * 64;
      if (l < LL) {
        float dist = 0.f;
        for (int jj = 0; jj < DY; jj++) {
          float diff = ys[w][p * 32 + jj] - u[(size_t)l * DY + jj];
          dist += diff * diff;
        }
        unsigned long long pk = ((unsigned long long)__float_as_uint(dist) << 32) | (unsigned)l;
        best = best < pk ? best : pk;
      }
    }
#pragma unroll
    for (int off = 32; off > 0; off >>= 1) {
      unsigned long long o = __shfl_xor(best, off, 64);
      best = best < o ? best : o;
    }
    if (lane == 0) (p ? yid2 : yid1)[b] = (int)(best & 0xffffffffull);
  }
}

// ---------------- k_eld: eldT[l][b] = exp(-eta * ld[l][yid[b]]) ----------------
__global__ __launch_bounds__(256) void k_eld(
    const float* __restrict__ ld1, const float* __restrict__ ld2,
    const int* __restrict__ yid1, const int* __restrict__ yid2,
    float* __restrict__ eldT1, float* __restrict__ eldT2)
{
  int idx = blockIdx.x * 256 + threadIdx.x;
  if (idx >= LL * NQ) return;
  int l = idx >> 11, b = idx & (NQ - 1);
  const float* ld = blockIdx.y ? ld2 : ld1;
  const int* yid = blockIdx.y ? yid2 : yid1;
  float* dst = blockIdx.y ? eldT2 : eldT1;
  dst[idx] = __expf(-0.01f * ld[l * LL + yid[b]]);
}

// ---------------- K3: flash-style e2 pass, both branches via blockIdx.z ----------------
__global__ __launch_bounds__(256, 6) void k_out(
    const unsigned short* __restrict__ xtb1, const unsigned short* __restrict__ xtb2,
    const unsigned short* __restrict__ f1_rm, const unsigned short* __restrict__ f2_rm,
    const unsigned short* __restrict__ vt2,
    const float* __restrict__ nf1l, const float* __restrict__ nf2l,
    const int* __restrict__ lidxp1, const int* __restrict__ lidxp2,
    const float* __restrict__ eldT1, const float* __restrict__ eldT2,
    float* __restrict__ qacc1, float* __restrict__ qacc2,
    float* __restrict__ qsacc1, float* __restrict__ qsacc2)
{
  __shared__ __align__(16) unsigned short plds[4][2][16 * PSTR];
  const int t0 = blockIdx.y * TPC;
  if (t0 >= NT) return;
  const int t1 = min(t0 + TPC, NT);
  const int br = blockIdx.z;
  const unsigned short* xtb = br ? xtb2 : xtb1;
  const unsigned short* f_rm = br ? f2_rm : f1_rm;
  const float* nfl = br ? nf2l : nf1l;
  const int* lidxp = br ? lidxp2 : lidxp1;
  const float* eldT = br ? eldT2 : eldT1;
  float* qacc = br ? qacc2 : qacc1;
  float* qsacc = br ? qsacc2 : qsacc1;

  const int w = threadIdx.x >> 6, lane = threadIdx.x & 63;
  const int col = lane & 15, quad = lane >> 4;
  const int b0 = blockIdx.x * 64 + w * 16;
  const int bq = b0 + col;

  bfrag xf0 = *(const bfrag*)(xtb + (size_t)bq * DD + quad * 8);
  bfrag xf1 = *(const bfrag*)(xtb + (size_t)bq * DD + 32 + quad * 8);

  ffrag acc[3];
#pragma unroll
  for (int n = 0; n < 3; n++) acc[n] = (ffrag){0.f, 0.f, 0.f, 0.f};

  for (int t = t0; t < t1; ++t) {
    unsigned short* myp = &plds[w][t & 1][0];
    const int i0 = t * 64;
#pragma unroll
    for (int m = 0; m < 4; m++) {
      const int ib = i0 + m * 16;
      bfrag a0 = *(const bfrag*)(f_rm + (size_t)(ib + col) * DD + quad * 8);
      bfrag a1 = *(const bfrag*)(f_rm + (size_t)(ib + col) * DD + 32 + quad * 8);
      ffrag c = (ffrag){0.f, 0.f, 0.f, 0.f};
      c = __builtin_amdgcn_mfma_f32_16x16x32_bf16(a0, xf0, c, 0, 0, 0);
      c = __builtin_amdgcn_mfma_f32_16x16x32_bf16(a1, xf1, c, 0, 0, 0);
      float4 nfv = *(const float4*)(nfl + ib + quad * 4);
      int4 lv = *(const int4*)(lidxp + ib + quad * 4);
      float g0 = eldT[(size_t)lv.x * NQ + bq];
      float g1 = eldT[(size_t)lv.y * NQ + bq];
      float g2 = eldT[(size_t)lv.z * NQ + bq];
      float g3 = eldT[(size_t)lv.w * NQ + bq];
      float e0 = EXP2(c[0] - nfv.x) * g0;
      float e1 = EXP2(c[1] - nfv.y) * g1;
      float e2 = EXP2(c[2] - nfv.z) * g2;
      float e3 = EXP2(c[3] - nfv.w) * g3;
      unsigned int p01 = (unsigned int)bf16rne(e0) | ((unsigned int)bf16rne(e1) << 16);
      unsigned int p23 = (unsigned int)bf16rne(e2) | ((unsigned int)bf16rne(e3) << 16);
      *(uint2*)(myp + col * PSTR + m * 16 + quad * 4) = make_uint2(p01, p23);
    }
    bfrag pa0 = *(const bfrag*)(myp + col * PSTR + quad * 8);
    bfrag pa1 = *(const bfrag*)(myp + col * PSTR + 32 + quad * 8);
#pragma unroll
    for (int n = 0; n < 3; n++) {
      bfrag v0 = *(const bfrag*)(vt2 + (size_t)(n * 16 + col) * NSP + i0 + quad * 8);
      bfrag v1 = *(const bfrag*)(vt2 + (size_t)(n * 16 + col) * NSP + i0 + 32 + quad * 8);
      acc[n] = __builtin_amdgcn_mfma_f32_16x16x32_bf16(pa0, v0, acc[n], 0, 0, 0);
      acc[n] = __builtin_amdgcn_mfma_f32_16x16x32_bf16(pa1, v1, acc[n], 0, 0, 0);
    }
  }

  const int brow = b0 + quad * 4;
#pragma unroll
  for (int n = 0; n < 2; n++)
#pragma unroll
    for (int r = 0; r < 4; r++)
      atomicAdd(qacc + (size_t)(brow + r) * DY + n * 16 + col, acc[n][r]);
  if (col == 0) {
#pragma unroll
    for (int r = 0; r < 4; r++) atomicAdd(qsacc + brow + r, acc[2][r]);
  }
}

// ---------------- K4: final divide + average ----------------
__global__ __launch_bounds__(256) void k_fin(
    const float* __restrict__ q1, const float* __restrict__ qs1,
    const float* __restrict__ q2, const float* __restrict__ qs2,
    float* __restrict__ out)
{
  int t = blockIdx.x * 256 + threadIdx.x;
  if (t >= NQ * DY) return;
  int b = t >> 5;
  out[t] = 0.5f * (q1[t] / qs1[b] + q2[t] / qs2[b]);
}

extern "C" void kernel_launch(void* const* d_in, const int* in_sizes, int n_in,
                              void* d_out, int out_size, void* d_ws, size_t ws_size,
                              hipStream_t stream)
{
  const float* x    = (const float*)d_in[0];
  const float* star = (const float*)d_in[1];
  const float* slab = (const float*)d_in[2];
  const float* f1   = (const float*)d_in[3];
  const float* f2   = (const float*)d_in[4];
  const float* u1   = (const float*)d_in[5];
  const float* u2   = (const float*)d_in[6];
  const float* ld1  = (const float*)d_in[7];
  const float* ld2  = (const float*)d_in[8];
  const float* W1   = (const float*)d_in[9];
  const float* b1   = (const float*)d_in[10];
  const float* W2   = (const float*)d_in[11];
  const float* b2   = (const float*)d_in[12];
  const int* lidx1  = (const int*)d_in[13];
  const int* lidx2  = (const int*)d_in[14];
  float* out = (float*)d_out;

  char* base = (char*)d_ws;
  size_t off = 0;
  auto alloc = [&](size_t bytes) -> char* {
    char* p = base + off;
    off = (off + bytes + 255) & ~(size_t)255;
    return p;
  };
  // zeroed accumulators first (single memset region)
  float* xtacc1 = (float*)alloc(NQ * DD * 4);
  float* xtacc2 = (float*)alloc(NQ * DD * 4);
  float* qacc1  = (float*)alloc(NQ * DY * 4);
  float* qacc2  = (float*)alloc(NQ * DY * 4);
  float* sacc   = (float*)alloc(NQ * 4);
  float* qsacc1 = (float*)alloc(NQ * 4);
  float* qsacc2 = (float*)alloc(NQ * 4);
  const size_t zeroBytes = off;
  unsigned short* xb     = (unsigned short*)alloc((size_t)NQ * DD * 2);
  unsigned short* star_b = (unsigned short*)alloc((size_t)NSP * DD * 2);
  unsigned short* f1_rm  = (unsigned short*)alloc((size_t)NSP * DD * 2);
  unsigned short* f2_rm  = (unsigned short*)alloc((size_t)NSP * DD * 2);
  unsigned short* vt1    = (unsigned short*)alloc((size_t)144 * NSP * 2);
  unsigned short* vt2    = (unsigned short*)alloc((size_t)48 * NSP * 2);
  unsigned short* xtb1   = (unsigned short*)alloc((size_t)NQ * DD * 2);
  unsigned short* xtb2   = (unsigned short*)alloc((size_t)NQ * DD * 2);
  float* nsl   = (float*)alloc(NSP * 4);
  float* nf1l  = (float*)alloc(NSP * 4);
  float* nf2l  = (float*)alloc(NSP * 4);
  float* nxl   = (float*)alloc(NQ * 4);
  float* eldT1 = (float*)alloc((size_t)LL * NQ * 4);
  float* eldT2 = (float*)alloc((size_t)LL * NQ * 4);
  int* lidxp1 = (int*)alloc(NSP * 4);
  int* lidxp2 = (int*)alloc(NSP * 4);
  int* matchIdx = (int*)alloc(NQ * 4);
  int* yid1 = (int*)alloc(NQ * 4);
  int* yid2 = (int*)alloc(NQ * 4);

  hipMemsetAsync(d_ws, 0, zeroBytes, stream);

  k_prepA<<<NT, 256, 0, stream>>>(
      star, f1, f2, slab, lidx1, lidx2,
      star_b, f1_rm, f2_rm, vt1, vt2, nsl, nf1l, nf2l, lidxp1, lidxp2);
  k_prepB<<<NQ / 256, 256, 0, stream>>>(x, xb, nxl, matchIdx);

  k_star<<<dim3(NQ / 64, NCH), 256, 0, stream>>>(
      xb, star_b, vt1, nsl, nxl, xtacc1, xtacc2, sacc, matchIdx);

  k_mid<<<NQ / 4, 256, 0, stream>>>(
      xtacc1, xtacc2, sacc, matchIdx, f1, f2, W1, b1, W2, b2, u1, u2,
      xtb1, xtb2, yid1, yid2);

  k_eld<<<dim3((LL * NQ + 255) / 256, 2), 256, 0, stream>>>(
      ld1, ld2, yid1, yid2, eldT1, eldT2);

  k_out<<<dim3(NQ / 64, NCH, 2), 256, 0, stream>>>(
      xtb1, xtb2, f1_rm, f2_rm, vt2, nf1l, nf2l, lidxp1, lidxp2,
      eldT1, eldT2, qacc1, qacc2, qsacc1, qsacc2);

  k_fin<<<(NQ * DY + 255) / 256, 256, 0, stream>>>(qacc1, qsacc1, qacc2, qsacc2, out);
}

// Round 5
// 313.169 us; speedup vs baseline: 6.2608x; 1.3973x over previous
//
#include <hip/hip_runtime.h>
#include <cstddef>

#define NQ 2048    // batch B
#define NS 20000   // stars N
#define NSP 20032  // NS padded to 64
#define DD 64      // feature dim
#define DY 32      // label dim
#define LL 100     // unique labels
#define NT 313     // i-tiles of 64 (NSP/64)
#define PSTR 72    // P-tile LDS row stride in shorts
#define LOG2E 1.4426950408889634f
#define NELD (-0.01f * 1.4426950408889634f)  // -eta*log2e

typedef __attribute__((ext_vector_type(8))) short bfrag;   // 8 bf16 (A/B operand)
typedef __attribute__((ext_vector_type(4))) float ffrag;   // 4 f32  (C/D operand)

#if __has_builtin(__builtin_amdgcn_exp2f)
#define EXP2(x) __builtin_amdgcn_exp2f(x)
#else
#define EXP2(x) exp2f(x)
#endif

__device__ __forceinline__ unsigned short bf16rne(float v) {
  unsigned int u = __float_as_uint(v);
  u += 0x7FFFu + ((u >> 16) & 1u);
  return (unsigned short)(u >> 16);
}

__device__ __forceinline__ uint4 pack8(const unsigned short* o) {
  uint4 q;
  q.x = (unsigned int)o[0] | ((unsigned int)o[1] << 16);
  q.y = (unsigned int)o[2] | ((unsigned int)o[3] << 16);
  q.z = (unsigned int)o[4] | ((unsigned int)o[5] << 16);
  q.w = (unsigned int)o[6] | ((unsigned int)o[7] << 16);
  return q;
}

// ---------------- prepA: per 64-i tile: bf16 converts, norms, transposes ----------------
__global__ __launch_bounds__(256) void k_prepA(
    const float* __restrict__ star, const float* __restrict__ f1,
    const float* __restrict__ f2, const float* __restrict__ slab,
    const int* __restrict__ lidx1, const int* __restrict__ lidx2,
    unsigned short* __restrict__ star_b, unsigned short* __restrict__ f1_rm,
    unsigned short* __restrict__ f2_rm, unsigned short* __restrict__ vt1,
    unsigned short* __restrict__ vt2,
    float* __restrict__ nsl, float* __restrict__ nf1l, float* __restrict__ nf2l,
    int* __restrict__ lidxp1, int* __restrict__ lidxp2)
{
  __shared__ float tile[64][65];
  const int i0 = blockIdx.x * 64;
  const int tid = threadIdx.x;
  const int r = tid >> 2, cs = (tid & 3) * 16;
  const int dT = tid >> 2, is = (tid & 3) * 16;
  const bool okr = (i0 + r) < NS;

  const float* srcs[3] = {star, f1, f2};
  unsigned short* dsts[3] = {star_b, f1_rm, f2_rm};
  float* norms[3] = {nsl, nf1l, nf2l};
#pragma unroll 1
  for (int a = 0; a < 3; a++) {
    float v[16];
    const float* src = srcs[a] + (size_t)(i0 + r) * DD + cs;
#pragma unroll
    for (int q = 0; q < 4; q++) {
      float4 t4 = okr ? *(const float4*)(src + q * 4) : make_float4(0.f, 0.f, 0.f, 0.f);
      v[4*q+0] = t4.x; v[4*q+1] = t4.y; v[4*q+2] = t4.z; v[4*q+3] = t4.w;
    }
    unsigned short ob[16];
#pragma unroll
    for (int j = 0; j < 16; j++) { ob[j] = bf16rne(v[j]); tile[r][cs + j] = v[j]; }
    *(uint4*)(dsts[a] + (size_t)(i0 + r) * DD + cs) = pack8(ob);
    *(uint4*)(dsts[a] + (size_t)(i0 + r) * DD + cs + 8) = pack8(ob + 8);
    __syncthreads();
    if (tid < 64) {
      float s = 0.f;
      for (int d = 0; d < DD; d++) s += tile[tid][d] * tile[tid][d];
      norms[a][i0 + tid] = (i0 + tid) < NS ? LOG2E * s : 1e30f;
    }
    if (a > 0) {  // vt1 rows: a==1 -> 0..63 (f1^T), a==2 -> 64..127 (f2^T)
      unsigned short tb[16];
#pragma unroll
      for (int j = 0; j < 16; j++) tb[j] = bf16rne(tile[is + j][dT]);
      unsigned short* dst = vt1 + (size_t)((a - 1) * DD + dT) * NSP + i0 + is;
      *(uint4*)dst = pack8(tb);
      *(uint4*)(dst + 8) = pack8(tb + 8);
    }
    __syncthreads();
  }

  // slab (64 x 32) -> vt2 rows 0..31
  if (tid < 128) {
    const int r2 = tid >> 1, cs2 = (tid & 1) * 16;
    const bool ok2 = (i0 + r2) < NS;
    const float* src = slab + (size_t)(i0 + r2) * DY + cs2;
#pragma unroll
    for (int q = 0; q < 4; q++) {
      float4 t4 = ok2 ? *(const float4*)(src + q * 4) : make_float4(0.f, 0.f, 0.f, 0.f);
      tile[r2][cs2+4*q+0] = t4.x; tile[r2][cs2+4*q+1] = t4.y;
      tile[r2][cs2+4*q+2] = t4.z; tile[r2][cs2+4*q+3] = t4.w;
    }
  }
  __syncthreads();
  if (tid < 128) {
    const int d2 = tid >> 2, is2 = (tid & 3) * 16;
    unsigned short tb[16];
#pragma unroll
    for (int j = 0; j < 16; j++) tb[j] = bf16rne(tile[is2 + j][d2]);
    unsigned short* dst = vt2 + (size_t)d2 * NSP + i0 + is2;
    *(uint4*)dst = pack8(tb);
    *(uint4*)(dst + 8) = pack8(tb + 8);
  }
  if (tid < 64) {
    int i = i0 + tid;
    bool ok = i < NS;
    lidxp1[i] = ok ? lidx1[i] : 0;
    lidxp2[i] = ok ? lidx2[i] : 0;
  }
}

// ---------------- prepB: xb = bf16(x * 2log2e), nxl, matchIdx ----------------
__global__ __launch_bounds__(256) void k_prepB(
    const float* __restrict__ x, unsigned short* __restrict__ xb,
    float* __restrict__ nxl, int* __restrict__ matchIdx)
{
  int b = blockIdx.x * 256 + threadIdx.x;
  if (b >= NQ) return;
  const float* px = x + (size_t)b * DD;
  float s = 0.f;
  for (int d = 0; d < DD; d += 4) {
    float4 v = *(const float4*)(px + d);
    s += v.x*v.x + v.y*v.y + v.z*v.z + v.w*v.w;
    unsigned int lo = (unsigned int)bf16rne(v.x * (2.f * LOG2E)) |
                      ((unsigned int)bf16rne(v.y * (2.f * LOG2E)) << 16);
    unsigned int hi = (unsigned int)bf16rne(v.z * (2.f * LOG2E)) |
                      ((unsigned int)bf16rne(v.w * (2.f * LOG2E)) << 16);
    *(uint2*)(xb + (size_t)b * DD + d) = make_uint2(lo, hi);
  }
  nxl[b] = LOG2E * s;
  matchIdx[b] = NS;
}

// ---------------- K1: flash-style e_star pass, 64i x 32b per wave ----------------
// GEMM1: S^T[i,b]; P = exp2(S - nsl[i]); GEMM2: xtp[k][b][0..127] = P . vt1
// esum kept in registers (quad shuffle-reduce at end). No atomics.
__global__ __launch_bounds__(256, 3) void k_star(
    const unsigned short* __restrict__ xb, const unsigned short* __restrict__ star_b,
    const unsigned short* __restrict__ vt1, const float* __restrict__ nsl,
    const float* __restrict__ nxl,
    float* __restrict__ xtp, float* __restrict__ sump,
    int* __restrict__ matchIdx, int nch)
{
  __shared__ __align__(16) unsigned short plds[4][32 * PSTR];  // 18432 B
  const int w = threadIdx.x >> 6, lane = threadIdx.x & 63;
  const int col = lane & 15, quad = lane >> 4;
  const int b0 = blockIdx.x * 128 + w * 32;
  const int bqa = b0 + col, bqb = b0 + 16 + col;
  const int k = blockIdx.y;
  const int t0 = (k * NT) / nch, t1 = ((k + 1) * NT) / nch;
  unsigned short* myp = &plds[w][0];

  bfrag xa0 = *(const bfrag*)(xb + (size_t)bqa * DD + quad * 8);
  bfrag xa1 = *(const bfrag*)(xb + (size_t)bqa * DD + 32 + quad * 8);
  bfrag xb0 = *(const bfrag*)(xb + (size_t)bqb * DD + quad * 8);
  bfrag xb1 = *(const bfrag*)(xb + (size_t)bqb * DD + 32 + quad * 8);
  const float nxa = nxl[bqa], nxbv = nxl[bqb];

  ffrag acc[8][2];
#pragma unroll
  for (int n = 0; n < 8; n++) {
    acc[n][0] = (ffrag){0.f, 0.f, 0.f, 0.f};
    acc[n][1] = (ffrag){0.f, 0.f, 0.f, 0.f};
  }
  float es0 = 0.f, es1 = 0.f;
  int lmin0 = NS, lmin1 = NS;

  for (int t = t0; t < t1; ++t) {
    const int i0 = t * 64;
#pragma unroll
    for (int m = 0; m < 4; m++) {
      const int ib = i0 + m * 16;
      bfrag a0 = *(const bfrag*)(star_b + (size_t)(ib + col) * DD + quad * 8);
      bfrag a1 = *(const bfrag*)(star_b + (size_t)(ib + col) * DD + 32 + quad * 8);
      ffrag c0 = (ffrag){0.f, 0.f, 0.f, 0.f};
      ffrag c1 = (ffrag){0.f, 0.f, 0.f, 0.f};
      c0 = __builtin_amdgcn_mfma_f32_16x16x32_bf16(a0, xa0, c0, 0, 0, 0);
      c0 = __builtin_amdgcn_mfma_f32_16x16x32_bf16(a1, xa1, c0, 0, 0, 0);
      c1 = __builtin_amdgcn_mfma_f32_16x16x32_bf16(a0, xb0, c1, 0, 0, 0);
      c1 = __builtin_amdgcn_mfma_f32_16x16x32_bf16(a1, xb1, c1, 0, 0, 0);
      float4 nsv = *(const float4*)(nsl + ib + quad * 4);
      const int ibase = ib + quad * 4;
      unsigned short p0[4], p1[4];
#pragma unroll
      for (int r = 0; r < 4; r++) {
        float ns_r = (r == 0) ? nsv.x : (r == 1) ? nsv.y : (r == 2) ? nsv.z : nsv.w;
        float g0 = c0[r] - ns_r;
        float g1 = c1[r] - ns_r;
        if (g0 >= nxa) lmin0 = min(lmin0, ibase + r);
        if (g1 >= nxbv) lmin1 = min(lmin1, ibase + r);
        float e0 = EXP2(g0), e1 = EXP2(g1);
        es0 += e0; es1 += e1;
        p0[r] = bf16rne(e0); p1[r] = bf16rne(e1);
      }
      *(uint2*)(myp + col * PSTR + m * 16 + quad * 4) =
          make_uint2((unsigned)p0[0] | ((unsigned)p0[1] << 16),
                     (unsigned)p0[2] | ((unsigned)p0[3] << 16));
      *(uint2*)(myp + (col + 16) * PSTR + m * 16 + quad * 4) =
          make_uint2((unsigned)p1[0] | ((unsigned)p1[1] << 16),
                     (unsigned)p1[2] | ((unsigned)p1[3] << 16));
    }
    // wave-private LDS; same-wave DS ordering (no barrier)
    bfrag pa0 = *(const bfrag*)(myp + col * PSTR + quad * 8);
    bfrag pa1 = *(const bfrag*)(myp + col * PSTR + 32 + quad * 8);
    bfrag pb0 = *(const bfrag*)(myp + (col + 16) * PSTR + quad * 8);
    bfrag pb1 = *(const bfrag*)(myp + (col + 16) * PSTR + 32 + quad * 8);
#pragma unroll
    for (int n = 0; n < 8; n++) {
      bfrag v0 = *(const bfrag*)(vt1 + (size_t)(n * 16 + col) * NSP + i0 + quad * 8);
      bfrag v1 = *(const bfrag*)(vt1 + (size_t)(n * 16 + col) * NSP + i0 + 32 + quad * 8);
      acc[n][0] = __builtin_amdgcn_mfma_f32_16x16x32_bf16(pa0, v0, acc[n][0], 0, 0, 0);
      acc[n][0] = __builtin_amdgcn_mfma_f32_16x16x32_bf16(pa1, v1, acc[n][0], 0, 0, 0);
      acc[n][1] = __builtin_amdgcn_mfma_f32_16x16x32_bf16(pb0, v0, acc[n][1], 0, 0, 0);
      acc[n][1] = __builtin_amdgcn_mfma_f32_16x16x32_bf16(pb1, v1, acc[n][1], 0, 0, 0);
    }
  }

  // epilogue: plain coalesced partial stores
#pragma unroll
  for (int h = 0; h < 2; h++)
#pragma unroll
    for (int n = 0; n < 8; n++)
#pragma unroll
      for (int r = 0; r < 4; r++) {
        int b = b0 + h * 16 + quad * 4 + r;
        xtp[((size_t)k * NQ + b) * 128 + n * 16 + col] = acc[n][h][r];
      }
  es0 += __shfl_xor(es0, 16, 64); es0 += __shfl_xor(es0, 32, 64);
  es1 += __shfl_xor(es1, 16, 64); es1 += __shfl_xor(es1, 32, 64);
  if (quad == 0) {
    sump[(size_t)k * NQ + b0 + col] = es0;
    sump[(size_t)k * NQ + b0 + 16 + col] = es1;
  }
  if (lmin0 < NS) atomicMin(matchIdx + bqa, lmin0);
  if (lmin1 < NS) atomicMin(matchIdx + bqb, lmin1);
}

// ---------------- K2: reduce partials -> xt, xtb, y = xt@W+b, y_idx ----------------
__global__ __launch_bounds__(256) void k_mid(
    const float* __restrict__ xtp, const float* __restrict__ sump,
    const int* __restrict__ matchIdx,
    const float* __restrict__ f1, const float* __restrict__ f2,
    const float* __restrict__ W1, const float* __restrict__ b1,
    const float* __restrict__ W2, const float* __restrict__ b2,
    const float* __restrict__ u1, const float* __restrict__ u2,
    unsigned short* __restrict__ xtb1, unsigned short* __restrict__ xtb2,
    int* __restrict__ yid1, int* __restrict__ yid2, int nch)
{
  __shared__ float xts[2][4][64];
  __shared__ float ys[4][64];
  const int lane = threadIdx.x & 63;
  const int w = __builtin_amdgcn_readfirstlane(threadIdx.x >> 6);
  const int b = blockIdx.x * 4 + w;

  float s1 = 0.f, s2 = 0.f, S = 0.f;
  for (int kk = 0; kk < nch; kk++) {
    const float* row = xtp + ((size_t)kk * NQ + b) * 128;
    s1 += row[lane];
    s2 += row[64 + lane];
    S  += sump[(size_t)kk * NQ + b];
  }
  const int m = matchIdx[b];
  float xa, xb_;
  if (m < NS) {
    xa = f1[(size_t)m * DD + lane];
    xb_ = f2[(size_t)m * DD + lane];
  } else {
    xa = s1 / S;
    xb_ = s2 / S;
  }
  xtb1[(size_t)b * DD + lane] = bf16rne(xa * (2.f * LOG2E));
  xtb2[(size_t)b * DD + lane] = bf16rne(xb_ * (2.f * LOG2E));
  xts[0][w][lane] = xa;
  xts[1][w][lane] = xb_;
  __syncthreads();

  const int half = lane >> 5;
  const int j = lane & 31;
  const float* W = half ? W2 : W1;
  float y = (half ? b2 : b1)[j];
  for (int d = 0; d < DD; d++) y += xts[half][w][d] * W[d * DY + j];
  ys[w][lane] = y;
  __syncthreads();

#pragma unroll
  for (int p = 0; p < 2; p++) {
    const float* u = p ? u2 : u1;
    unsigned long long best = ~0ull;
#pragma unroll
    for (int h = 0; h < 2; h++) {
      int l = lane + h * 64;
      if (l < LL) {
        float dist = 0.f;
        for (int jj = 0; jj < DY; jj++) {
          float diff = ys[w][p * 32 + jj] - u[(size_t)l * DY + jj];
          dist += diff * diff;
        }
        unsigned long long pk = ((unsigned long long)__float_as_uint(dist) << 32) | (unsigned)l;
        best = best < pk ? best : pk;
      }
    }
#pragma unroll
    for (int off = 32; off > 0; off >>= 1) {
      unsigned long long o = __shfl_xor(best, off, 64);
      best = best < o ? best : o;
    }
    if (lane == 0) (p ? yid2 : yid1)[b] = (int)(best & 0xffffffffull);
  }
}

// ---------------- k_eld: lgP[(l*64+bb)*16+col] = {-eta*log2e*ld[l][yid[b]], ...[b+16]} ----------------
__global__ __launch_bounds__(256) void k_eld(
    const float* __restrict__ ld1, const float* __restrict__ ld2,
    const int* __restrict__ yid1, const int* __restrict__ yid2,
    float2* __restrict__ lgP1, float2* __restrict__ lgP2)
{
  int t = blockIdx.x * 256 + threadIdx.x;
  if (t >= LL * 64 * 16) return;
  const float* ld = blockIdx.y ? ld2 : ld1;
  const int* yid = blockIdx.y ? yid2 : yid1;
  float2* dst = blockIdx.y ? lgP2 : lgP1;
  int l = t >> 10, bb = (t >> 4) & 63, col = t & 15;
  int b = bb * 32 + col;
  dst[t] = make_float2(NELD * ld[l * LL + yid[b]], NELD * ld[l * LL + yid[b + 16]]);
}

// ---------------- K3: flash-style e2 pass, 64i x 32b per wave, both branches ----------------
__global__ __launch_bounds__(256, 4) void k_out(
    const unsigned short* __restrict__ xtb1, const unsigned short* __restrict__ xtb2,
    const unsigned short* __restrict__ f1_rm, const unsigned short* __restrict__ f2_rm,
    const unsigned short* __restrict__ vt2,
    const float* __restrict__ nf1l, const float* __restrict__ nf2l,
    const int* __restrict__ lidxp1, const int* __restrict__ lidxp2,
    const float2* __restrict__ lgP1, const float2* __restrict__ lgP2,
    float* __restrict__ qp1, float* __restrict__ qp2,
    float* __restrict__ qsp1, float* __restrict__ qsp2, int nch)
{
  __shared__ __align__(16) unsigned short plds[4][32 * PSTR];
  const int br = blockIdx.z;
  const unsigned short* xtb = br ? xtb2 : xtb1;
  const unsigned short* f_rm = br ? f2_rm : f1_rm;
  const float* nfl = br ? nf2l : nf1l;
  const int* lidxp = br ? lidxp2 : lidxp1;
  const float2* lgP = br ? lgP2 : lgP1;
  float* qp = br ? qp2 : qp1;
  float* qsp = br ? qsp2 : qsp1;

  const int w = threadIdx.x >> 6, lane = threadIdx.x & 63;
  const int col = lane & 15, quad = lane >> 4;
  const int b0 = blockIdx.x * 128 + w * 32;
  const int bb = blockIdx.x * 4 + w;
  const int bqa = b0 + col, bqb = b0 + 16 + col;
  const int k = blockIdx.y;
  const int t0 = (k * NT) / nch, t1 = ((k + 1) * NT) / nch;
  unsigned short* myp = &plds[w][0];

  bfrag xa0 = *(const bfrag*)(xtb + (size_t)bqa * DD + quad * 8);
  bfrag xa1 = *(const bfrag*)(xtb + (size_t)bqa * DD + 32 + quad * 8);
  bfrag xc0 = *(const bfrag*)(xtb + (size_t)bqb * DD + quad * 8);
  bfrag xc1 = *(const bfrag*)(xtb + (size_t)bqb * DD + 32 + quad * 8);

  ffrag acc[2][2];
#pragma unroll
  for (int n = 0; n < 2; n++) {
    acc[n][0] = (ffrag){0.f, 0.f, 0.f, 0.f};
    acc[n][1] = (ffrag){0.f, 0.f, 0.f, 0.f};
  }
  float es0 = 0.f, es1 = 0.f;

  for (int t = t0; t < t1; ++t) {
    const int i0 = t * 64;
#pragma unroll
    for (int m = 0; m < 4; m++) {
      const int ib = i0 + m * 16;
      bfrag a0 = *(const bfrag*)(f_rm + (size_t)(ib + col) * DD + quad * 8);
      bfrag a1 = *(const bfrag*)(f_rm + (size_t)(ib + col) * DD + 32 + quad * 8);
      ffrag c0 = (ffrag){0.f, 0.f, 0.f, 0.f};
      ffrag c1 = (ffrag){0.f, 0.f, 0.f, 0.f};
      c0 = __builtin_amdgcn_mfma_f32_16x16x32_bf16(a0, xa0, c0, 0, 0, 0);
      c0 = __builtin_amdgcn_mfma_f32_16x16x32_bf16(a1, xa1, c0, 0, 0, 0);
      c1 = __builtin_amdgcn_mfma_f32_16x16x32_bf16(a0, xc0, c1, 0, 0, 0);
      c1 = __builtin_amdgcn_mfma_f32_16x16x32_bf16(a1, xc1, c1, 0, 0, 0);
      float4 nfv = *(const float4*)(nfl + ib + quad * 4);
      int4 lv = *(const int4*)(lidxp + ib + quad * 4);
      float2 g0 = lgP[((size_t)lv.x * 64 + bb) * 16 + col];
      float2 g1 = lgP[((size_t)lv.y * 64 + bb) * 16 + col];
      float2 g2 = lgP[((size_t)lv.z * 64 + bb) * 16 + col];
      float2 g3 = lgP[((size_t)lv.w * 64 + bb) * 16 + col];
      float ea0 = EXP2(c0[0] - nfv.x + g0.x), eb0 = EXP2(c1[0] - nfv.x + g0.y);
      float ea1 = EXP2(c0[1] - nfv.y + g1.x), eb1 = EXP2(c1[1] - nfv.y + g1.y);
      float ea2 = EXP2(c0[2] - nfv.z + g2.x), eb2 = EXP2(c1[2] - nfv.z + g2.y);
      float ea3 = EXP2(c0[3] - nfv.w + g3.x), eb3 = EXP2(c1[3] - nfv.w + g3.y);
      es0 += ea0 + ea1 + ea2 + ea3;
      es1 += eb0 + eb1 + eb2 + eb3;
      *(uint2*)(myp + col * PSTR + m * 16 + quad * 4) =
          make_uint2((unsigned)bf16rne(ea0) | ((unsigned)bf16rne(ea1) << 16),
                     (unsigned)bf16rne(ea2) | ((unsigned)bf16rne(ea3) << 16));
      *(uint2*)(myp + (col + 16) * PSTR + m * 16 + quad * 4) =
          make_uint2((unsigned)bf16rne(eb0) | ((unsigned)bf16rne(eb1) << 16),
                     (unsigned)bf16rne(eb2) | ((unsigned)bf16rne(eb3) << 16));
    }
    bfrag pa0 = *(const bfrag*)(myp + col * PSTR + quad * 8);
    bfrag pa1 = *(const bfrag*)(myp + col * PSTR + 32 + quad * 8);
    bfrag pb0 = *(const bfrag*)(myp + (col + 16) * PSTR + quad * 8);
    bfrag pb1 = *(const bfrag*)(myp + (col + 16) * PSTR + 32 + quad * 8);
#pragma unroll
    for (int n = 0; n < 2; n++) {
      bfrag v0 = *(const bfrag*)(vt2 + (size_t)(n * 16 + col) * NSP + i0 + quad * 8);
      bfrag v1 = *(const bfrag*)(vt2 + (size_t)(n * 16 + col) * NSP + i0 + 32 + quad * 8);
      acc[n][0] = __builtin_amdgcn_mfma_f32_16x16x32_bf16(pa0, v0, acc[n][0], 0, 0, 0);
      acc[n][0] = __builtin_amdgcn_mfma_f32_16x16x32_bf16(pa1, v1, acc[n][0], 0, 0, 0);
      acc[n][1] = __builtin_amdgcn_mfma_f32_16x16x32_bf16(pb0, v0, acc[n][1], 0, 0, 0);
      acc[n][1] = __builtin_amdgcn_mfma_f32_16x16x32_bf16(pb1, v1, acc[n][1], 0, 0, 0);
    }
  }

#pragma unroll
  for (int h = 0; h < 2; h++)
#pragma unroll
    for (int n = 0; n < 2; n++)
#pragma unroll
      for (int r = 0; r < 4; r++) {
        int b = b0 + h * 16 + quad * 4 + r;
        qp[((size_t)k * NQ + b) * DY + n * 16 + col] = acc[n][h][r];
      }
  es0 += __shfl_xor(es0, 16, 64); es0 += __shfl_xor(es0, 32, 64);
  es1 += __shfl_xor(es1, 16, 64); es1 += __shfl_xor(es1, 32, 64);
  if (quad == 0) {
    qsp[(size_t)k * NQ + b0 + col] = es0;
    qsp[(size_t)k * NQ + b0 + 16 + col] = es1;
  }
}

// ---------------- K4: reduce partials + average ----------------
__global__ __launch_bounds__(256) void k_fin(
    const float* __restrict__ qp1, const float* __restrict__ qsp1,
    const float* __restrict__ qp2, const float* __restrict__ qsp2,
    float* __restrict__ out, int nch)
{
  int t = blockIdx.x * 256 + threadIdx.x;
  if (t >= NQ * DY) return;
  int b = t >> 5, j = t & 31;
  float n1 = 0.f, d1 = 0.f, n2 = 0.f, d2 = 0.f;
  for (int kk = 0; kk < nch; kk++) {
    n1 += qp1[((size_t)kk * NQ + b) * DY + j];
    n2 += qp2[((size_t)kk * NQ + b) * DY + j];
    d1 += qsp1[(size_t)kk * NQ + b];
    d2 += qsp2[(size_t)kk * NQ + b];
  }
  out[t] = 0.5f * (n1 / d1 + n2 / d2);
}

extern "C" void kernel_launch(void* const* d_in, const int* in_sizes, int n_in,
                              void* d_out, int out_size, void* d_ws, size_t ws_size,
                              hipStream_t stream)
{
  const float* x    = (const float*)d_in[0];
  const float* star = (const float*)d_in[1];
  const float* slab = (const float*)d_in[2];
  const float* f1   = (const float*)d_in[3];
  const float* f2   = (const float*)d_in[4];
  const float* u1   = (const float*)d_in[5];
  const float* u2   = (const float*)d_in[6];
  const float* ld1  = (const float*)d_in[7];
  const float* ld2  = (const float*)d_in[8];
  const float* W1   = (const float*)d_in[9];
  const float* b1   = (const float*)d_in[10];
  const float* W2   = (const float*)d_in[11];
  const float* b2   = (const float*)d_in[12];
  const int* lidx1  = (const int*)d_in[13];
  const int* lidx2  = (const int*)d_in[14];
  float* out = (float*)d_out;

  // fixed aux bytes (all sizes already 256-aligned except small ones)
  auto al = [](size_t b) { return (b + 255) & ~(size_t)255; };
  const size_t auxBytes =
      al((size_t)NQ * DD * 2) +           // xb
      3 * al((size_t)NSP * DD * 2) +      // star_b, f1_rm, f2_rm
      al((size_t)128 * NSP * 2) +         // vt1
      al((size_t)32 * NSP * 2) +          // vt2
      2 * al((size_t)NQ * DD * 2) +       // xtb1/2
      3 * al((size_t)NSP * 4) +           // nsl,nf1l,nf2l
      al((size_t)NQ * 4) +                // nxl
      2 * al((size_t)LL * 64 * 16 * 8) +  // lgP1/2
      2 * al((size_t)NSP * 4) +           // lidxp1/2
      3 * al((size_t)NQ * 4);             // matchIdx, yid1, yid2
  const size_t perChunk = (size_t)NQ * 4 * (128 + 1 + 2 * DY + 2);  // xtp,sump,qp1/2,qsp1/2
  int nch = 48;
  while (nch > 6 && auxBytes + (size_t)nch * perChunk > ws_size) nch >>= 1;

  char* base = (char*)d_ws;
  size_t off = 0;
  auto alloc = [&](size_t bytes) -> char* {
    char* p = base + off;
    off = (off + bytes + 255) & ~(size_t)255;
    return p;
  };
  float* xtp  = (float*)alloc((size_t)nch * NQ * 128 * 4);
  float* sump = (float*)alloc((size_t)nch * NQ * 4);
  float* qp1  = (float*)alloc((size_t)nch * NQ * DY * 4);
  float* qp2  = (float*)alloc((size_t)nch * NQ * DY * 4);
  float* qsp1 = (float*)alloc((size_t)nch * NQ * 4);
  float* qsp2 = (float*)alloc((size_t)nch * NQ * 4);
  unsigned short* xb     = (unsigned short*)alloc((size_t)NQ * DD * 2);
  unsigned short* star_b = (unsigned short*)alloc((size_t)NSP * DD * 2);
  unsigned short* f1_rm  = (unsigned short*)alloc((size_t)NSP * DD * 2);
  unsigned short* f2_rm  = (unsigned short*)alloc((size_t)NSP * DD * 2);
  unsigned short* vt1    = (unsigned short*)alloc((size_t)128 * NSP * 2);
  unsigned short* vt2    = (unsigned short*)alloc((size_t)32 * NSP * 2);
  unsigned short* xtb1   = (unsigned short*)alloc((size_t)NQ * DD * 2);
  unsigned short* xtb2   = (unsigned short*)alloc((size_t)NQ * DD * 2);
  float* nsl   = (float*)alloc(NSP * 4);
  float* nf1l  = (float*)alloc(NSP * 4);
  float* nf2l  = (float*)alloc(NSP * 4);
  float* nxl   = (float*)alloc(NQ * 4);
  float2* lgP1 = (float2*)alloc((size_t)LL * 64 * 16 * 8);
  float2* lgP2 = (float2*)alloc((size_t)LL * 64 * 16 * 8);
  int* lidxp1 = (int*)alloc(NSP * 4);
  int* lidxp2 = (int*)alloc(NSP * 4);
  int* matchIdx = (int*)alloc(NQ * 4);
  int* yid1 = (int*)alloc(NQ * 4);
  int* yid2 = (int*)alloc(NQ * 4);

  k_prepA<<<NT, 256, 0, stream>>>(
      star, f1, f2, slab, lidx1, lidx2,
      star_b, f1_rm, f2_rm, vt1, vt2, nsl, nf1l, nf2l, lidxp1, lidxp2);
  k_prepB<<<NQ / 256, 256, 0, stream>>>(x, xb, nxl, matchIdx);

  k_star<<<dim3(NQ / 128, nch), 256, 0, stream>>>(
      xb, star_b, vt1, nsl, nxl, xtp, sump, matchIdx, nch);

  k_mid<<<NQ / 4, 256, 0, stream>>>(
      xtp, sump, matchIdx, f1, f2, W1, b1, W2, b2, u1, u2,
      xtb1, xtb2, yid1, yid2, nch);

  k_eld<<<dim3((LL * 64 * 16 + 255) / 256, 2), 256, 0, stream>>>(
      ld1, ld2, yid1, yid2, lgP1, lgP2);

  k_out<<<dim3(NQ / 128, nch, 2), 256, 0, stream>>>(
      xtb1, xtb2, f1_rm, f2_rm, vt2, nf1l, nf2l, lidxp1, lidxp2,
      lgP1, lgP2, qp1, qp2, qsp1, qsp2, nch);

  k_fin<<<(NQ * DY + 255) / 256, 256, 0, stream>>>(qp1, qsp1, qp2, qsp2, out, nch);
}